// Round 1
// baseline (355.495 us; speedup 1.0000x reference)
//
#include <hip/hip_runtime.h>
#include <math.h>

#define S_TOK 8192
#define M_DIM 4096
#define NEXP 64
#define CAPACITY 256   // K * ceil(S/E) = 2*128
#define NCHUNK 128     // S / 64

// ---------------------------------------------------------------------------
// K1: logits = x @ wg^T  (fp32 vector GEMM, 32 tok x 64 exp tile, BK=64,
//     double-buffered LDS) fused with softmax + top-2 + gate-norm + me accum.
// ---------------------------------------------------------------------------
__global__ __launch_bounds__(256) void k_gate(
    const float* __restrict__ x, const float* __restrict__ wg,
    float* __restrict__ me_g, int* __restrict__ idx0_g, int* __restrict__ idx1_g,
    float* __restrict__ gn0_g, float* __restrict__ gn1_g)
{
    constexpr int BT = 32, BK = 64;
    __shared__ __align__(16) float xs[2][BK][BT + 1];      // [buf][k][tok], pad 33
    __shared__ __align__(16) float wsl[2][BK][NEXP + 4];   // [buf][k][exp], pad 68 (16B-aligned rows)
    __shared__ float lgs[BT][NEXP + 1];
    __shared__ float me_sh[NEXP];

    const int tid = threadIdx.x;
    const int t0 = blockIdx.x * BT;
    if (tid < NEXP) me_sh[tid] = 0.f;

    const int tx = tid & 15;        // expert quad: experts 4*tx..4*tx+3
    const int ty = tid >> 4;        // token pair:  tokens 2*ty..2*ty+1
    float acc[2][4] = {{0.f,0.f,0.f,0.f},{0.f,0.f,0.f,0.f}};

    float4 rx[2], rw[4];
    const float* xb = x + (size_t)t0 * M_DIM;

    auto ldchunk = [&](int kc) {
        #pragma unroll
        for (int i = 0; i < 2; ++i) {
            int item = tid + 256 * i, tok = item >> 4, kq = item & 15;
            rx[i] = *(const float4*)(xb + (size_t)tok * M_DIM + kc + 4 * kq);
        }
        #pragma unroll
        for (int i = 0; i < 4; ++i) {
            int item = tid + 256 * i, e = item >> 4, kq = item & 15;
            rw[i] = *(const float4*)(wg + (size_t)e * M_DIM + kc + 4 * kq);
        }
    };
    auto stchunk = [&](int buf) {
        #pragma unroll
        for (int i = 0; i < 2; ++i) {
            int item = tid + 256 * i, tok = item >> 4, kq = item & 15;
            xs[buf][4*kq+0][tok] = rx[i].x;
            xs[buf][4*kq+1][tok] = rx[i].y;
            xs[buf][4*kq+2][tok] = rx[i].z;
            xs[buf][4*kq+3][tok] = rx[i].w;
        }
        #pragma unroll
        for (int i = 0; i < 4; ++i) {
            int item = tid + 256 * i, e = item >> 4, kq = item & 15;
            wsl[buf][4*kq+0][e] = rw[i].x;
            wsl[buf][4*kq+1][e] = rw[i].y;
            wsl[buf][4*kq+2][e] = rw[i].z;
            wsl[buf][4*kq+3][e] = rw[i].w;
        }
    };

    ldchunk(0);
    stchunk(0);
    __syncthreads();
    const int NC = M_DIM / BK;
    for (int c = 0; c < NC; ++c) {
        const int buf = c & 1;
        if (c + 1 < NC) ldchunk((c + 1) * BK);   // prefetch next chunk to regs
        #pragma unroll 16
        for (int kk = 0; kk < BK; ++kk) {
            float a0 = xs[buf][kk][2*ty];
            float a1 = xs[buf][kk][2*ty + 1];
            const float4 b = *(const float4*)&wsl[buf][kk][4*tx];
            acc[0][0] = fmaf(a0, b.x, acc[0][0]);
            acc[0][1] = fmaf(a0, b.y, acc[0][1]);
            acc[0][2] = fmaf(a0, b.z, acc[0][2]);
            acc[0][3] = fmaf(a0, b.w, acc[0][3]);
            acc[1][0] = fmaf(a1, b.x, acc[1][0]);
            acc[1][1] = fmaf(a1, b.y, acc[1][1]);
            acc[1][2] = fmaf(a1, b.z, acc[1][2]);
            acc[1][3] = fmaf(a1, b.w, acc[1][3]);
        }
        __syncthreads();
        if (c + 1 < NC) stchunk(buf ^ 1);
        __syncthreads();
    }

    // ---- epilogue: per-token softmax + top-2 over 64 experts ----
    #pragma unroll
    for (int i = 0; i < 2; ++i)
        #pragma unroll
        for (int j = 0; j < 4; ++j)
            lgs[2*ty + i][4*tx + j] = acc[i][j];
    __syncthreads();

    const int wv = tid >> 6, lane = tid & 63;
    float me_acc = 0.f;
    for (int i = 0; i < 8; ++i) {
        const int t = wv * 8 + i;
        const float lg = lgs[t][lane];

        // argmax (lowest index on tie, matching lax.top_k)
        float v = lg; int id = lane;
        #pragma unroll
        for (int off = 32; off > 0; off >>= 1) {
            float v2 = __shfl_xor(v, off);
            int   i2 = __shfl_xor(id, off);
            if (v2 > v || (v2 == v && i2 < id)) { v = v2; id = i2; }
        }
        const float mx = v; const int i0 = id;

        const float p = expf(lg - mx);
        float sum = p;
        #pragma unroll
        for (int off = 32; off > 0; off >>= 1) sum += __shfl_xor(sum, off);
        me_acc += p / sum;   // this lane's softmax gate, accumulated for me[e]

        // second argmax, excluding i0
        float v1 = (lane == i0) ? -INFINITY : lg; int id1 = lane;
        #pragma unroll
        for (int off = 32; off > 0; off >>= 1) {
            float v2 = __shfl_xor(v1, off);
            int   i2 = __shfl_xor(id1, off);
            if (v2 > v1 || (v2 == v1 && i2 < id1)) { v1 = v2; id1 = i2; }
        }

        const float g0 = 1.0f / sum;            // exp(mx-mx)/sum
        const float g1 = expf(v1 - mx) / sum;
        const float den = fmaxf(g0 + g1, 1.1920929e-07f);  // finfo(f32).eps
        if (lane == 0) {
            const int gs = t0 + t;
            idx0_g[gs] = i0;
            idx1_g[gs] = id1;
            gn0_g[gs] = g0 / den;
            gn1_g[gs] = g1 / den;
        }
    }
    atomicAdd(&me_sh[lane], me_acc);
    __syncthreads();
    if (tid < NEXP) atomicAdd(&me_g[tid], me_sh[tid]);
}

// ---------------------------------------------------------------------------
// K2: per-chunk (64 tokens) in-order ranks + histograms via 64-bit ballots.
// ---------------------------------------------------------------------------
__global__ __launch_bounds__(64) void k_rank(
    const int* __restrict__ idx0_g, const int* __restrict__ idx1_g,
    int* __restrict__ rank0_g, int* __restrict__ rank1_g,
    int* __restrict__ cnt_g /* [2][NCHUNK][64] */)
{
    const int lane = threadIdx.x;
    const int chunk = blockIdx.x;
    const int s = chunk * 64 + lane;
    const int e0 = idx0_g[s], e1 = idx1_g[s];
    const unsigned long long lt = (1ull << lane) - 1ull;

    int r0 = 0, r1 = 0, c0 = 0, c1 = 0;
    #pragma unroll
    for (int e = 0; e < 64; ++e) {
        unsigned long long m0 = __ballot(e0 == e);
        unsigned long long m1 = __ballot(e1 == e);
        if (e0 == e) r0 = __popcll(m0 & lt);
        if (e1 == e) r1 = __popcll(m1 & lt);
        if (lane == e) { c0 = __popcll(m0); c1 = __popcll(m1); }
    }
    rank0_g[s] = r0;
    rank1_g[s] = r1;
    cnt_g[chunk * 64 + lane] = c0;
    cnt_g[NCHUNK * 64 + chunk * 64 + lane] = c1;
}

// ---------------------------------------------------------------------------
// K3: exclusive scan over chunks per (k,e); ce/tot0; l_loss.
// ---------------------------------------------------------------------------
__global__ __launch_bounds__(128) void k_scan(
    const int* __restrict__ cnt_g, int* __restrict__ base_g,
    int* __restrict__ tot0_g, const float* __restrict__ me_g,
    float* __restrict__ loss_out)
{
    __shared__ float red[NEXP];
    const int tid = threadIdx.x;
    const int k = tid >> 6, e = tid & 63;
    const int* cnt = cnt_g + k * NCHUNK * 64 + e;
    int* base = base_g + k * NCHUNK * 64 + e;
    int run = 0;
    #pragma unroll 8
    for (int c = 0; c < NCHUNK; ++c) {
        base[c * 64] = run;
        run += cnt[c * 64];
    }
    if (k == 0) {
        tot0_g[e] = run;                       // counts[0][e] == ce[e]
        red[e] = me_g[e] * (float)run;
    }
    __syncthreads();
    if (tid == 0) {
        float t = 0.f;
        for (int i = 0; i < NEXP; ++i) t += red[i];
        *loss_out = t * (float)(64.0 / (8192.0 * 8192.0));
    }
}

// ---------------------------------------------------------------------------
// K4: out[s,:] = (valid0*gn0 + valid1*gn1) * x[s,:]
// ---------------------------------------------------------------------------
__global__ __launch_bounds__(256) void k_out(
    const float* __restrict__ x, float* __restrict__ out,
    const int* __restrict__ idx0_g, const int* __restrict__ idx1_g,
    const float* __restrict__ gn0_g, const float* __restrict__ gn1_g,
    const int* __restrict__ rank0_g, const int* __restrict__ rank1_g,
    const int* __restrict__ base_g, const int* __restrict__ tot0_g)
{
    __shared__ float wsh;
    const int s = blockIdx.x;
    const int tid = threadIdx.x;
    if (tid == 0) {
        const int chunk = s >> 6;
        const int e0 = idx0_g[s], e1 = idx1_g[s];
        const int loc0 = base_g[chunk * 64 + e0] + rank0_g[s];
        const int loc1 = base_g[NCHUNK * 64 + chunk * 64 + e1] + rank1_g[s] + tot0_g[e1];
        float w = 0.f;
        if (loc0 < CAPACITY) w += gn0_g[s];
        if (loc1 < CAPACITY) w += gn1_g[s];
        wsh = w;
    }
    __syncthreads();
    const float w = wsh;
    const float4* xr = (const float4*)(x + (size_t)s * M_DIM);
    float4* orow = (float4*)(out + (size_t)s * M_DIM);
    #pragma unroll
    for (int i = 0; i < 4; ++i) {
        float4 v = xr[tid + 256 * i];
        v.x *= w; v.y *= w; v.z *= w; v.w *= w;
        orow[tid + 256 * i] = v;
    }
}

// ---------------------------------------------------------------------------
extern "C" void kernel_launch(void* const* d_in, const int* in_sizes, int n_in,
                              void* d_out, int out_size, void* d_ws, size_t ws_size,
                              hipStream_t stream)
{
    const float* x  = (const float*)d_in[0];
    const float* wg = (const float*)d_in[1];
    float* out = (float*)d_out;

    // ws layout (4B elements):
    float* me   = (float*)d_ws;              // [64]
    int*  idx0  = (int*)d_ws + 64;           // [S]
    int*  idx1  = idx0 + S_TOK;              // [S]
    float* gn0  = (float*)(idx1 + S_TOK);    // [S]
    float* gn1  = gn0 + S_TOK;               // [S]
    int*  rank0 = (int*)(gn1 + S_TOK);       // [S]
    int*  rank1 = rank0 + S_TOK;             // [S]
    int*  cnt   = rank1 + S_TOK;             // [2][128][64]
    int*  base  = cnt + 2 * NCHUNK * 64;     // [2][128][64]
    int*  tot0  = base + 2 * NCHUNK * 64;    // [64]

    hipMemsetAsync(me, 0, NEXP * sizeof(float), stream);
    k_gate<<<S_TOK / 32, 256, 0, stream>>>(x, wg, me, idx0, idx1, gn0, gn1);
    k_rank<<<NCHUNK, 64, 0, stream>>>(idx0, idx1, rank0, rank1, cnt);
    k_scan<<<1, 128, 0, stream>>>(cnt, base, tot0, me,
                                  out + (size_t)S_TOK * M_DIM);
    k_out<<<S_TOK, 256, 0, stream>>>(x, out, idx0, idx1, gn0, gn1,
                                     rank0, rank1, base, tot0);
}

// Round 2
// 310.815 us; speedup vs baseline: 1.1438x; 1.1438x over previous
//
#include <hip/hip_runtime.h>
#include <math.h>

#define S_TOK 8192
#define M_DIM 4096
#define NEXP 64
#define CAPACITY 256   // K * ceil(S/E) = 2*128
#define NCHUNK 128     // S / 64
#define KS 8           // split-K slices
#define KSL 512        // slice length (KS*KSL = M_DIM)
#define BT 64          // tokens per tile
#define BK 32          // k per LDS chunk
#define NC (KSL / BK)  // 16 chunks per slice

// ---------------------------------------------------------------------------
// K1: partial logits, split-K. Grid 1024 = 128 token-tiles x 8 k-slices.
// 4tok x 4exp register tile; XOR-swizzled LDS (no padding, ~2-way max).
// ---------------------------------------------------------------------------
__global__ __launch_bounds__(256) void k_logits(
    const float* __restrict__ x, const float* __restrict__ wg,
    float* __restrict__ part)
{
    __shared__ float xs[2][BK * 64];
    __shared__ float wsl[2][BK * 64];
    const int tid = threadIdx.x;
    const int tile = blockIdx.x >> 3;      // 0..127
    const int ks   = blockIdx.x & 7;       // 0..7
    const int t0 = tile * BT;
    const int kb = ks * KSL;

    const int tx = tid & 15;               // experts 4*tx..4*tx+3
    const int ty = tid >> 4;               // tokens  4*ty..4*ty+3

    float4 rx[2], rw[2];
    auto ld = [&](int kc) {
        #pragma unroll
        for (int i = 0; i < 2; ++i) {
            const int item = tid + 256 * i;
            const int r = item >> 3, kq = item & 7;   // r: tok/exp row, kq: k-quad
            rx[i] = *(const float4*)(x  + (size_t)(t0 + r) * M_DIM + kc + 4 * kq);
            rw[i] = *(const float4*)(wg + (size_t)r       * M_DIM + kc + 4 * kq);
        }
    };
    auto st = [&](int buf) {
        #pragma unroll
        for (int i = 0; i < 2; ++i) {
            const int item = tid + 256 * i;
            const int r = item >> 3, kq = item & 7;
            const int quad = r >> 2, lo = r & 3;
            const float vx[4] = {rx[i].x, rx[i].y, rx[i].z, rx[i].w};
            const float vw[4] = {rw[i].x, rw[i].y, rw[i].z, rw[i].w};
            #pragma unroll
            for (int j = 0; j < 4; ++j) {
                const int row = 4 * kq + j;            // row>>2 == kq
                const int addr = row * 64 + ((quad ^ kq) << 2) + lo;
                xs[buf][addr]  = vx[j];
                wsl[buf][addr] = vw[j];
            }
        }
    };

    float acc[4][4] = {};
    ld(kb);
    st(0);
    __syncthreads();
    for (int c = 0; c < NC; ++c) {
        const int buf = c & 1;
        if (c + 1 < NC) ld(kb + (c + 1) * BK);
        #pragma unroll 8
        for (int kk = 0; kk < BK; ++kk) {
            const int sw = kk >> 2;
            const float4 a = *(const float4*)&xs [buf][kk * 64 + ((ty ^ sw) << 2)];
            const float4 b = *(const float4*)&wsl[buf][kk * 64 + ((tx ^ sw) << 2)];
            const float av[4] = {a.x, a.y, a.z, a.w};
            const float bv[4] = {b.x, b.y, b.z, b.w};
            #pragma unroll
            for (int i = 0; i < 4; ++i)
                #pragma unroll
                for (int j = 0; j < 4; ++j)
                    acc[i][j] = fmaf(av[i], bv[j], acc[i][j]);
        }
        __syncthreads();
        if (c + 1 < NC) st(buf ^ 1);
        __syncthreads();
    }

    #pragma unroll
    for (int i = 0; i < 4; ++i) {
        float4 v;
        v.x = acc[i][0]; v.y = acc[i][1]; v.z = acc[i][2]; v.w = acc[i][3];
        *(float4*)(part + ((size_t)ks * S_TOK + t0 + 4 * ty + i) * NEXP + 4 * tx) = v;
    }
}

// ---------------------------------------------------------------------------
// K2: reduce partials (deterministic slice order) + softmax + top-2 + me.
// One wave per 8 tokens, lane = expert.
// ---------------------------------------------------------------------------
__global__ __launch_bounds__(256) void k_reduce(
    const float* __restrict__ part, float* __restrict__ me_g,
    int* __restrict__ idx0_g, int* __restrict__ idx1_g,
    float* __restrict__ gn0_g, float* __restrict__ gn1_g)
{
    __shared__ float me_sh[NEXP];
    const int tid = threadIdx.x;
    if (tid < NEXP) me_sh[tid] = 0.f;
    __syncthreads();

    const int wv = tid >> 6, lane = tid & 63;
    float me_acc = 0.f;
    for (int i = 0; i < 8; ++i) {
        const int t = blockIdx.x * 32 + wv * 8 + i;
        float lg = 0.f;
        #pragma unroll
        for (int s = 0; s < KS; ++s)
            lg += part[((size_t)s * S_TOK + t) * NEXP + lane];

        // argmax (lowest index on tie, matching lax.top_k)
        float v = lg; int id = lane;
        #pragma unroll
        for (int off = 32; off > 0; off >>= 1) {
            float v2 = __shfl_xor(v, off);
            int   i2 = __shfl_xor(id, off);
            if (v2 > v || (v2 == v && i2 < id)) { v = v2; id = i2; }
        }
        const float mx = v; const int i0 = id;

        const float p = expf(lg - mx);
        float sum = p;
        #pragma unroll
        for (int off = 32; off > 0; off >>= 1) sum += __shfl_xor(sum, off);
        me_acc += p / sum;

        // second argmax, excluding i0
        float v1 = (lane == i0) ? -INFINITY : lg; int id1 = lane;
        #pragma unroll
        for (int off = 32; off > 0; off >>= 1) {
            float v2 = __shfl_xor(v1, off);
            int   i2 = __shfl_xor(id1, off);
            if (v2 > v1 || (v2 == v1 && i2 < id1)) { v1 = v2; id1 = i2; }
        }

        const float g0 = 1.0f / sum;
        const float g1 = expf(v1 - mx) / sum;
        const float den = fmaxf(g0 + g1, 1.1920929e-07f);
        if (lane == 0) {
            idx0_g[t] = i0;
            idx1_g[t] = id1;
            gn0_g[t] = g0 / den;
            gn1_g[t] = g1 / den;
        }
    }
    atomicAdd(&me_sh[lane], me_acc);
    __syncthreads();
    if (tid < NEXP) atomicAdd(&me_g[tid], me_sh[tid]);
}

// ---------------------------------------------------------------------------
// K3: per-chunk (64 tokens) in-order ranks + histograms via 64-bit ballots.
// ---------------------------------------------------------------------------
__global__ __launch_bounds__(64) void k_rank(
    const int* __restrict__ idx0_g, const int* __restrict__ idx1_g,
    int* __restrict__ rank0_g, int* __restrict__ rank1_g,
    int* __restrict__ cnt_g /* [2][NCHUNK][64] */)
{
    const int lane = threadIdx.x;
    const int chunk = blockIdx.x;
    const int s = chunk * 64 + lane;
    const int e0 = idx0_g[s], e1 = idx1_g[s];
    const unsigned long long lt = (1ull << lane) - 1ull;

    int r0 = 0, r1 = 0, c0 = 0, c1 = 0;
    #pragma unroll
    for (int e = 0; e < 64; ++e) {
        unsigned long long m0 = __ballot(e0 == e);
        unsigned long long m1 = __ballot(e1 == e);
        if (e0 == e) r0 = __popcll(m0 & lt);
        if (e1 == e) r1 = __popcll(m1 & lt);
        if (lane == e) { c0 = __popcll(m0); c1 = __popcll(m1); }
    }
    rank0_g[s] = r0;
    rank1_g[s] = r1;
    cnt_g[chunk * 64 + lane] = c0;
    cnt_g[NCHUNK * 64 + chunk * 64 + lane] = c1;
}

// ---------------------------------------------------------------------------
// K4: parallel scan — one wave per (k,e), shfl prefix over 128 chunks.
// Also emits ce (tot0) and the load-balance loss.
// ---------------------------------------------------------------------------
__global__ __launch_bounds__(256) void k_scan(
    const int* __restrict__ cnt_g, int* __restrict__ base_g,
    int* __restrict__ tot0_g, const float* __restrict__ me_g,
    float* __restrict__ loss_out)
{
    const int wv = threadIdx.x >> 6, lane = threadIdx.x & 63;
    const int g = blockIdx.x * 4 + wv;         // 0..127
    const int k = g >> 6, e = g & 63;

    const int c0 = cnt_g[(k * NCHUNK + 2 * lane)     * 64 + e];
    const int c1 = cnt_g[(k * NCHUNK + 2 * lane + 1) * 64 + e];
    const int s = c0 + c1;
    int incl = s;
    #pragma unroll
    for (int d = 1; d < 64; d <<= 1) {
        int v = __shfl_up(incl, d);
        if (lane >= d) incl += v;
    }
    const int excl = incl - s;
    base_g[(k * NCHUNK + 2 * lane)     * 64 + e] = excl;
    base_g[(k * NCHUNK + 2 * lane + 1) * 64 + e] = excl + c0;
    const int total = __shfl(incl, 63);
    if (k == 0 && lane == 0) {
        tot0_g[e] = total;
        atomicAdd(loss_out, me_g[e] * (float)total * 9.5367431640625e-07f); // E/S^2
    }
}

// ---------------------------------------------------------------------------
// K5: per-token combine weight (capacity check).
// ---------------------------------------------------------------------------
__global__ __launch_bounds__(256) void k_weight(
    const int* __restrict__ idx0_g, const int* __restrict__ idx1_g,
    const float* __restrict__ gn0_g, const float* __restrict__ gn1_g,
    const int* __restrict__ rank0_g, const int* __restrict__ rank1_g,
    const int* __restrict__ base_g, const int* __restrict__ tot0_g,
    float* __restrict__ w_g)
{
    const int s = blockIdx.x * 256 + threadIdx.x;
    const int chunk = s >> 6;
    const int e0 = idx0_g[s], e1 = idx1_g[s];
    const int loc0 = base_g[chunk * 64 + e0] + rank0_g[s];
    const int loc1 = base_g[(NCHUNK + chunk) * 64 + e1] + rank1_g[s] + tot0_g[e1];
    float w = 0.f;
    if (loc0 < CAPACITY) w += gn0_g[s];
    if (loc1 < CAPACITY) w += gn1_g[s];
    w_g[s] = w;
}

// ---------------------------------------------------------------------------
// K6: out[s,:] = w[s] * x[s,:]   (w is wave-uniform -> scalar load)
// ---------------------------------------------------------------------------
__global__ __launch_bounds__(256) void k_out(
    const float* __restrict__ x, const float* __restrict__ w_g,
    float* __restrict__ out)
{
    const int s = blockIdx.x;
    const float w = w_g[s];
    const float4* xr = (const float4*)(x + (size_t)s * M_DIM);
    float4* o = (float4*)(out + (size_t)s * M_DIM);
    #pragma unroll
    for (int i = 0; i < 4; ++i) {
        float4 v = xr[threadIdx.x + 256 * i];
        v.x *= w; v.y *= w; v.z *= w; v.w *= w;
        o[threadIdx.x + 256 * i] = v;
    }
}

// ---------------------------------------------------------------------------
extern "C" void kernel_launch(void* const* d_in, const int* in_sizes, int n_in,
                              void* d_out, int out_size, void* d_ws, size_t ws_size,
                              hipStream_t stream)
{
    const float* x  = (const float*)d_in[0];
    const float* wg = (const float*)d_in[1];
    float* out = (float*)d_out;
    float* loss = out + (size_t)S_TOK * M_DIM;

    // ws layout (floats/ints, 4B):
    float* part = (float*)d_ws;                         // [KS][S][E] = 16.78 MB
    float* me   = part + (size_t)KS * S_TOK * NEXP;     // [64]
    int*  idx0  = (int*)(me + NEXP);                    // [S]
    int*  idx1  = idx0 + S_TOK;                         // [S]
    float* gn0  = (float*)(idx1 + S_TOK);               // [S]
    float* gn1  = gn0 + S_TOK;                          // [S]
    int*  rank0 = (int*)(gn1 + S_TOK);                  // [S]
    int*  rank1 = rank0 + S_TOK;                        // [S]
    int*  cnt   = rank1 + S_TOK;                        // [2][128][64]
    int*  base  = cnt + 2 * NCHUNK * 64;                // [2][128][64]
    int*  tot0  = base + 2 * NCHUNK * 64;               // [64]
    float* wtok = (float*)(tot0 + NEXP);                // [S]

    hipMemsetAsync(me, 0, NEXP * sizeof(float), stream);
    hipMemsetAsync(loss, 0, sizeof(float), stream);

    k_logits<<<128 * KS, 256, 0, stream>>>(x, wg, part);
    k_reduce<<<S_TOK / 32, 256, 0, stream>>>(part, me, idx0, idx1, gn0, gn1);
    k_rank<<<NCHUNK, 64, 0, stream>>>(idx0, idx1, rank0, rank1, cnt);
    k_scan<<<32, 256, 0, stream>>>(cnt, base, tot0, me, loss);
    k_weight<<<S_TOK / 256, 256, 0, stream>>>(idx0, idx1, gn0, gn1,
                                              rank0, rank1, base, tot0, wtok);
    k_out<<<S_TOK, 256, 0, stream>>>(x, wtok, out);
}